// Round 2
// baseline (4005.681 us; speedup 1.0000x reference)
//
#include <hip/hip_runtime.h>
#include <math.h>

// Problem constants
#define DIN   4096
#define NST   16
#define RR    128
#define LSEQ  2048
#define NTOK  4096   // B*L

__device__ __forceinline__ float sigmoidf_(float x) { return 1.f / (1.f + __expf(-x)); }
__device__ __forceinline__ float softplusf_(float x) {
    return fmaxf(x, 0.f) + log1pf(__expf(-fabsf(x)));
}

// C[M,N] = A[M,K(lda)] * W[N,K]^T  (both operands read along K contiguously)
// 128x128 tile, BK=8, 256 threads, 8x8 per thread (4+4 split fragments).
// EPI==1: C = softplus(C + bias[col])
template<int EPI>
__global__ __launch_bounds__(256)
void gemm128_kernel(const float* __restrict__ A, const float* __restrict__ W,
                    float* __restrict__ C, int K, int lda, int ldw, int ldc,
                    const float* __restrict__ bias)
{
    __shared__ float As[8][128];
    __shared__ float Ws[8][128];
    const int tid = threadIdx.x;
    const int tx = tid & 15;
    const int ty = tid >> 4;
    const int bm = blockIdx.y << 7;
    const int bn = blockIdx.x << 7;
    const int lr = tid >> 1;          // 0..127
    const int lc = (tid & 1) << 2;    // 0 or 4

    const float* Ap = A + (size_t)(bm + lr) * lda + lc;
    const float* Wp = W + (size_t)(bn + lr) * ldw + lc;

    float acc[8][8] = {};

    for (int k0 = 0; k0 < K; k0 += 8) {
        float4 av = *(const float4*)Ap;
        float4 wv = *(const float4*)Wp;
        Ap += 8; Wp += 8;
        __syncthreads();   // previous tile's reads done before overwrite
        As[lc + 0][lr] = av.x; As[lc + 1][lr] = av.y;
        As[lc + 2][lr] = av.z; As[lc + 3][lr] = av.w;
        Ws[lc + 0][lr] = wv.x; Ws[lc + 1][lr] = wv.y;
        Ws[lc + 2][lr] = wv.z; Ws[lc + 3][lr] = wv.w;
        __syncthreads();
        #pragma unroll
        for (int kk = 0; kk < 8; ++kk) {
            float4 a0 = *(const float4*)&As[kk][ty * 4];
            float4 a1 = *(const float4*)&As[kk][64 + ty * 4];
            float4 w0 = *(const float4*)&Ws[kk][tx * 4];
            float4 w1 = *(const float4*)&Ws[kk][64 + tx * 4];
            float a[8] = {a0.x, a0.y, a0.z, a0.w, a1.x, a1.y, a1.z, a1.w};
            float w[8] = {w0.x, w0.y, w0.z, w0.w, w1.x, w1.y, w1.z, w1.w};
            #pragma unroll
            for (int i = 0; i < 8; ++i)
                #pragma unroll
                for (int j = 0; j < 8; ++j)
                    acc[i][j] = fmaf(a[i], w[j], acc[i][j]);
        }
    }

    #pragma unroll
    for (int i = 0; i < 8; ++i) {
        int r = bm + ((i < 4) ? (ty * 4 + i) : (64 + ty * 4 + i - 4));
        #pragma unroll
        for (int jh = 0; jh < 2; ++jh) {
            int c = bn + jh * 64 + tx * 4;
            float4 v;
            v.x = acc[i][jh * 4 + 0];
            v.y = acc[i][jh * 4 + 1];
            v.z = acc[i][jh * 4 + 2];
            v.w = acc[i][jh * 4 + 3];
            if (EPI == 1) {
                v.x = softplusf_(v.x + bias[c + 0]);
                v.y = softplusf_(v.y + bias[c + 1]);
                v.z = softplusf_(v.z + bias[c + 2]);
                v.w = softplusf_(v.w + bias[c + 3]);
            }
            *(float4*)&C[(size_t)r * ldc + c] = v;
        }
    }
}

// Tall-skinny GEMM for x_proj: C[M,160] = A[M,K] * W[160,K]^T
// 128x32 tile, BK=16, 256 threads, 8x2 per thread.
__global__ __launch_bounds__(256)
void gemm_skinny_kernel(const float* __restrict__ A, const float* __restrict__ W,
                        float* __restrict__ C, int K, int ldc)
{
    __shared__ float As[16][132];  // +4 pad: keeps b128 alignment, breaks store conflicts
    __shared__ float Ws[16][36];
    const int tid = threadIdx.x;
    const int tx = tid & 15;
    const int ty = tid >> 4;
    const int bm = blockIdx.y << 7;
    const int bn = blockIdx.x << 5;
    const int ar = tid >> 2;            // 0..63
    const int ac = (tid & 3) << 2;      // 0,4,8,12

    float acc[8][2] = {};

    for (int k0 = 0; k0 < K; k0 += 16) {
        float4 v0 = *(const float4*)&A[(size_t)(bm + ar) * K + k0 + ac];
        float4 v1 = *(const float4*)&A[(size_t)(bm + 64 + ar) * K + k0 + ac];
        float4 wv;
        if (tid < 128) wv = *(const float4*)&W[(size_t)(bn + (tid >> 2)) * K + k0 + ac];
        __syncthreads();
        As[ac + 0][ar] = v0.x; As[ac + 1][ar] = v0.y;
        As[ac + 2][ar] = v0.z; As[ac + 3][ar] = v0.w;
        As[ac + 0][64 + ar] = v1.x; As[ac + 1][64 + ar] = v1.y;
        As[ac + 2][64 + ar] = v1.z; As[ac + 3][64 + ar] = v1.w;
        if (tid < 128) {
            int wr = tid >> 2;
            Ws[ac + 0][wr] = wv.x; Ws[ac + 1][wr] = wv.y;
            Ws[ac + 2][wr] = wv.z; Ws[ac + 3][wr] = wv.w;
        }
        __syncthreads();
        #pragma unroll
        for (int kk = 0; kk < 16; ++kk) {
            float4 a0 = *(const float4*)&As[kk][ty * 4];
            float4 a1 = *(const float4*)&As[kk][64 + ty * 4];
            float2 w2 = *(const float2*)&Ws[kk][tx * 2];
            float a[8] = {a0.x, a0.y, a0.z, a0.w, a1.x, a1.y, a1.z, a1.w};
            #pragma unroll
            for (int i = 0; i < 8; ++i) {
                acc[i][0] = fmaf(a[i], w2.x, acc[i][0]);
                acc[i][1] = fmaf(a[i], w2.y, acc[i][1]);
            }
        }
    }

    #pragma unroll
    for (int i = 0; i < 8; ++i) {
        int r = bm + ((i < 4) ? (ty * 4 + i) : (64 + ty * 4 + i - 4));
        int c = bn + tx * 2;
        *(float2*)&C[(size_t)r * ldc + c] = make_float2(acc[i][0], acc[i][1]);
    }
}

// Causal depthwise conv (K=4) + SiLU.  x buffer is (NTOK, DIN) contiguous.
__global__ __launch_bounds__(256)
void conv_silu_kernel(const float* __restrict__ x, const float* __restrict__ cw,
                      float* __restrict__ xc)
{
    int idx = blockIdx.x * 256 + threadIdx.x;     // over NTOK*DIN
    int d = idx & (DIN - 1);
    int tok = idx >> 12;
    int t = tok & (LSEQ - 1);
    float w0 = cw[d * 4 + 0], w1 = cw[d * 4 + 1];
    float w2 = cw[d * 4 + 2], w3 = cw[d * 4 + 3];
    const float* xp = x + (size_t)tok * DIN + d;
    float acc = w3 * xp[0];
    if (t >= 1) acc = fmaf(w2, xp[-DIN], acc);
    if (t >= 2) acc = fmaf(w1, xp[-2 * DIN], acc);
    if (t >= 3) acc = fmaf(w0, xp[-3 * DIN], acc);
    xc[idx] = acc * sigmoidf_(acc);
}

// Selective scan: one thread per (b,d) channel, 16-state recurrence in registers.
// Fuses  y = (y_scan + xc*D) * silu(z)  and writes y in-place over xc.
__global__ __launch_bounds__(64)
void scan_kernel(const float* __restrict__ delta, float* __restrict__ xcy,
                 const float* __restrict__ xdbl, const float* __restrict__ z,
                 const float* __restrict__ A_log, const float* __restrict__ Dp)
{
    int d = blockIdx.x * 64 + threadIdx.x;
    int b = blockIdx.y;
    float A[NST], h[NST];
    #pragma unroll
    for (int n = 0; n < NST; ++n) {
        A[n] = -__expf(A_log[d * NST + n]);
        h[n] = 0.f;
    }
    float Dv = Dp[d];
    int tok = b * LSEQ;
    for (int t = 0; t < LSEQ; ++t, ++tok) {
        float dv = delta[(size_t)tok * DIN + d];
        float xv = xcy[(size_t)tok * DIN + d];
        float zv = z[(size_t)tok * DIN + d];
        const float* bc = xdbl + (size_t)tok * 160 + RR;   // B then C, 16 each
        float dx = dv * xv;
        float y = 0.f;
        #pragma unroll
        for (int n = 0; n < NST; ++n) {
            h[n] = fmaf(h[n], __expf(dv * A[n]), dx * bc[n]);
            y = fmaf(h[n], bc[NST + n], y);
        }
        y = (y + xv * Dv) * (zv * sigmoidf_(zv));
        xcy[(size_t)tok * DIN + d] = y;
    }
}

extern "C" void kernel_launch(void* const* d_in, const int* in_sizes, int n_in,
                              void* d_out, int out_size, void* d_ws, size_t ws_size,
                              hipStream_t stream)
{
    const float* hidden     = (const float*)d_in[0];  // (2,2048,2048)
    const float* in_proj_w  = (const float*)d_in[1];  // (8192,2048)
    const float* conv_w     = (const float*)d_in[2];  // (4096,4)
    const float* x_proj_w   = (const float*)d_in[3];  // (160,4096)
    const float* dt_proj_w  = (const float*)d_in[4];  // (4096,128)
    const float* dt_bias    = (const float*)d_in[5];  // (4096,)
    const float* A_log      = (const float*)d_in[6];  // (4096,16)
    const float* D_param    = (const float*)d_in[7];  // (4096,)
    const float* out_proj_w = (const float*)d_in[8];  // (2048,4096)
    float* out = (float*)d_out;                       // (2,2048,2048) fp32

    // Workspace layout: 3 x 67.1 MB + 2.6 MB = 204 MB total
    // xbuf: x (pre-conv) -> later reused for delta
    // xc:   conv output  -> y written in-place by scan
    // zbuf: z half of in_proj
    const size_t BIG = (size_t)NTOK * DIN * sizeof(float);   // 67,108,864 B
    char* ws = (char*)d_ws;
    float* xbuf = (float*)(ws);
    float* xc   = (float*)(ws + BIG);
    float* zbuf = (float*)(ws + 2 * BIG);
    float* xdbl = (float*)(ws + 3 * BIG);                    // 4096*160*4 = 2.6 MB
    float* delta = xbuf;                                     // reuse after conv

    // 1a) x = hidden @ in_proj_w[0:4096]^T        M=4096 N=4096 K=2048
    gemm128_kernel<0><<<dim3(32, 32), 256, 0, stream>>>(hidden, in_proj_w, xbuf,
                                                        2048, 2048, 2048, DIN, nullptr);
    // 1b) z = hidden @ in_proj_w[4096:8192]^T
    gemm128_kernel<0><<<dim3(32, 32), 256, 0, stream>>>(hidden,
                                                        in_proj_w + (size_t)DIN * 2048,
                                                        zbuf, 2048, 2048, 2048, DIN, nullptr);
    // 2) xc = silu(causal_conv(x))
    conv_silu_kernel<<<(NTOK * DIN) / 256, 256, 0, stream>>>(xbuf, conv_w, xc);
    // 3) x_dbl = xc @ x_proj_w^T                  M=4096 N=160 K=4096
    gemm_skinny_kernel<<<dim3(5, 32), 256, 0, stream>>>(xc, x_proj_w, xdbl, 4096, 160);
    // 4) delta = softplus(dt_r @ dt_proj_w^T + bias)   M=4096 N=4096 K=128 (lda=160)
    //    (delta overwrites xbuf — x is dead after the conv)
    gemm128_kernel<1><<<dim3(32, 32), 256, 0, stream>>>(xdbl, dt_proj_w, delta,
                                                        128, 160, 128, DIN, dt_bias);
    // 5) selective scan + (+xc*D)*silu(z), y overwrites xc
    scan_kernel<<<dim3(DIN / 64, 2), 64, 0, stream>>>(delta, xc, xdbl, zbuf, A_log, D_param);
    // 6) out = y @ out_proj_w^T                   M=4096 N=2048 K=4096
    gemm128_kernel<0><<<dim3(16, 32), 256, 0, stream>>>(xc, out_proj_w, out,
                                                        4096, 4096, 4096, 2048, nullptr);
}

// Round 3
// 3104.966 us; speedup vs baseline: 1.2901x; 1.2901x over previous
//
#include <hip/hip_runtime.h>
#include <math.h>

// Problem constants
#define DIN   4096
#define NST   16
#define RR    128
#define LSEQ  2048
#define NTOK  4096   // B*L
#define BB    2
#define CHUNK 64
#define NCH   (LSEQ / CHUNK)   // 32

__device__ __forceinline__ float sigmoidf_(float x) { return 1.f / (1.f + __expf(-x)); }
__device__ __forceinline__ float softplusf_(float x) {
    return fmaxf(x, 0.f) + log1pf(__expf(-fabsf(x)));
}

// C[M,N] = A[M,K(lda)] * W[N,K]^T  (both operands read along K contiguously)
// 128x128 tile, BK=8, 256 threads, 8x8 per thread (4+4 split fragments).
// EPI==1: C = softplus(C + bias[col])
template<int EPI>
__global__ __launch_bounds__(256)
void gemm128_kernel(const float* __restrict__ A, const float* __restrict__ W,
                    float* __restrict__ C, int K, int lda, int ldw, int ldc,
                    const float* __restrict__ bias)
{
    __shared__ float As[8][128];
    __shared__ float Ws[8][128];
    const int tid = threadIdx.x;
    const int tx = tid & 15;
    const int ty = tid >> 4;
    const int bm = blockIdx.y << 7;
    const int bn = blockIdx.x << 7;
    const int lr = tid >> 1;          // 0..127
    const int lc = (tid & 1) << 2;    // 0 or 4

    const float* Ap = A + (size_t)(bm + lr) * lda + lc;
    const float* Wp = W + (size_t)(bn + lr) * ldw + lc;

    float acc[8][8] = {};

    for (int k0 = 0; k0 < K; k0 += 8) {
        float4 av = *(const float4*)Ap;
        float4 wv = *(const float4*)Wp;
        Ap += 8; Wp += 8;
        __syncthreads();   // previous tile's reads done before overwrite
        As[lc + 0][lr] = av.x; As[lc + 1][lr] = av.y;
        As[lc + 2][lr] = av.z; As[lc + 3][lr] = av.w;
        Ws[lc + 0][lr] = wv.x; Ws[lc + 1][lr] = wv.y;
        Ws[lc + 2][lr] = wv.z; Ws[lc + 3][lr] = wv.w;
        __syncthreads();
        #pragma unroll
        for (int kk = 0; kk < 8; ++kk) {
            float4 a0 = *(const float4*)&As[kk][ty * 4];
            float4 a1 = *(const float4*)&As[kk][64 + ty * 4];
            float4 w0 = *(const float4*)&Ws[kk][tx * 4];
            float4 w1 = *(const float4*)&Ws[kk][64 + tx * 4];
            float a[8] = {a0.x, a0.y, a0.z, a0.w, a1.x, a1.y, a1.z, a1.w};
            float w[8] = {w0.x, w0.y, w0.z, w0.w, w1.x, w1.y, w1.z, w1.w};
            #pragma unroll
            for (int i = 0; i < 8; ++i)
                #pragma unroll
                for (int j = 0; j < 8; ++j)
                    acc[i][j] = fmaf(a[i], w[j], acc[i][j]);
        }
    }

    #pragma unroll
    for (int i = 0; i < 8; ++i) {
        int r = bm + ((i < 4) ? (ty * 4 + i) : (64 + ty * 4 + i - 4));
        #pragma unroll
        for (int jh = 0; jh < 2; ++jh) {
            int c = bn + jh * 64 + tx * 4;
            float4 v;
            v.x = acc[i][jh * 4 + 0];
            v.y = acc[i][jh * 4 + 1];
            v.z = acc[i][jh * 4 + 2];
            v.w = acc[i][jh * 4 + 3];
            if (EPI == 1) {
                v.x = softplusf_(v.x + bias[c + 0]);
                v.y = softplusf_(v.y + bias[c + 1]);
                v.z = softplusf_(v.z + bias[c + 2]);
                v.w = softplusf_(v.w + bias[c + 3]);
            }
            *(float4*)&C[(size_t)r * ldc + c] = v;
        }
    }
}

// Tall-skinny GEMM for x_proj: C[M,160] = A[M,K] * W[160,K]^T
// 128x32 tile, BK=16, 256 threads, 8x2 per thread.
__global__ __launch_bounds__(256)
void gemm_skinny_kernel(const float* __restrict__ A, const float* __restrict__ W,
                        float* __restrict__ C, int K, int ldc)
{
    __shared__ float As[16][132];  // +4 pad: keeps b128 alignment, breaks store conflicts
    __shared__ float Ws[16][36];
    const int tid = threadIdx.x;
    const int tx = tid & 15;
    const int ty = tid >> 4;
    const int bm = blockIdx.y << 7;
    const int bn = blockIdx.x << 5;
    const int ar = tid >> 2;            // 0..63
    const int ac = (tid & 3) << 2;      // 0,4,8,12

    float acc[8][2] = {};

    for (int k0 = 0; k0 < K; k0 += 16) {
        float4 v0 = *(const float4*)&A[(size_t)(bm + ar) * K + k0 + ac];
        float4 v1 = *(const float4*)&A[(size_t)(bm + 64 + ar) * K + k0 + ac];
        float4 wv;
        if (tid < 128) wv = *(const float4*)&W[(size_t)(bn + (tid >> 2)) * K + k0 + ac];
        __syncthreads();
        As[ac + 0][ar] = v0.x; As[ac + 1][ar] = v0.y;
        As[ac + 2][ar] = v0.z; As[ac + 3][ar] = v0.w;
        As[ac + 0][64 + ar] = v1.x; As[ac + 1][64 + ar] = v1.y;
        As[ac + 2][64 + ar] = v1.z; As[ac + 3][64 + ar] = v1.w;
        if (tid < 128) {
            int wr = tid >> 2;
            Ws[ac + 0][wr] = wv.x; Ws[ac + 1][wr] = wv.y;
            Ws[ac + 2][wr] = wv.z; Ws[ac + 3][wr] = wv.w;
        }
        __syncthreads();
        #pragma unroll
        for (int kk = 0; kk < 16; ++kk) {
            float4 a0 = *(const float4*)&As[kk][ty * 4];
            float4 a1 = *(const float4*)&As[kk][64 + ty * 4];
            float2 w2 = *(const float2*)&Ws[kk][tx * 2];
            float a[8] = {a0.x, a0.y, a0.z, a0.w, a1.x, a1.y, a1.z, a1.w};
            #pragma unroll
            for (int i = 0; i < 8; ++i) {
                acc[i][0] = fmaf(a[i], w2.x, acc[i][0]);
                acc[i][1] = fmaf(a[i], w2.y, acc[i][1]);
            }
        }
    }

    #pragma unroll
    for (int i = 0; i < 8; ++i) {
        int r = bm + ((i < 4) ? (ty * 4 + i) : (64 + ty * 4 + i - 4));
        int c = bn + tx * 2;
        *(float2*)&C[(size_t)r * ldc + c] = make_float2(acc[i][0], acc[i][1]);
    }
}

// Causal depthwise conv (K=4) + SiLU.  x buffer is (NTOK, DIN) contiguous.
__global__ __launch_bounds__(256)
void conv_silu_kernel(const float* __restrict__ x, const float* __restrict__ cw,
                      float* __restrict__ xc)
{
    int idx = blockIdx.x * 256 + threadIdx.x;     // over NTOK*DIN
    int d = idx & (DIN - 1);
    int tok = idx >> 12;
    int t = tok & (LSEQ - 1);
    float w0 = cw[d * 4 + 0], w1 = cw[d * 4 + 1];
    float w2 = cw[d * 4 + 2], w3 = cw[d * 4 + 3];
    const float* xp = x + (size_t)tok * DIN + d;
    float acc = w3 * xp[0];
    if (t >= 1) acc = fmaf(w2, xp[-DIN], acc);
    if (t >= 2) acc = fmaf(w1, xp[-2 * DIN], acc);
    if (t >= 3) acc = fmaf(w0, xp[-3 * DIN], acc);
    xc[idx] = acc * sigmoidf_(acc);
}

// ---- Chunked parallel selective scan --------------------------------------
// h[t] = exp(dv_t * A) * h[t-1] + dv_t*x_t*B_t ; A time-invariant per (d,n)
// => chunk transition is scalar per state: exp(A[n] * sum(dv over chunk)).
// S1: per (b,chunk,d) local recurrence from 0 -> hloc[16], delta-sum -> ssum.
__global__ __launch_bounds__(256)
void scan_part1_kernel(const float* __restrict__ delta, const float* __restrict__ xc,
                       const float* __restrict__ xdbl, const float* __restrict__ A_log,
                       float* __restrict__ hloc, float* __restrict__ ssum)
{
    int d = blockIdx.x * 256 + threadIdx.x;
    int c = blockIdx.y;
    int b = blockIdx.z;
    float A[NST], h[NST];
    #pragma unroll
    for (int n = 0; n < NST; ++n) {
        A[n] = -__expf(A_log[d * NST + n]);
        h[n] = 0.f;
    }
    float s = 0.f;
    int tok = b * LSEQ + c * CHUNK;
    for (int t = 0; t < CHUNK; ++t, ++tok) {
        float dv = delta[(size_t)tok * DIN + d];
        float xv = xc[(size_t)tok * DIN + d];
        const float* bc = xdbl + (size_t)tok * 160 + RR;
        float dx = dv * xv;
        s += dv;
        #pragma unroll
        for (int n = 0; n < NST; ++n)
            h[n] = fmaf(h[n], __expf(dv * A[n]), dx * bc[n]);
    }
    size_t base = (size_t)(b * NCH + c) * NST * DIN + d;
    #pragma unroll
    for (int n = 0; n < NST; ++n) hloc[base + (size_t)n * DIN] = h[n];
    ssum[(size_t)(b * NCH + c) * DIN + d] = s;
}

// S2: per (b,d) combine 32 chunks sequentially; store chunk-entry state
// in-place over hloc (read slot before overwrite).
__global__ __launch_bounds__(256)
void scan_part2_kernel(float* __restrict__ hloc, const float* __restrict__ ssum,
                       const float* __restrict__ A_log)
{
    int idx = blockIdx.x * 256 + threadIdx.x;   // over BB*DIN = 8192
    int b = idx >> 12;
    int d = idx & (DIN - 1);
    float A[NST], hin[NST];
    #pragma unroll
    for (int n = 0; n < NST; ++n) {
        A[n] = -__expf(A_log[d * NST + n]);
        hin[n] = 0.f;
    }
    for (int c = 0; c < NCH; ++c) {
        size_t base = (size_t)(b * NCH + c) * NST * DIN + d;
        float s = ssum[(size_t)(b * NCH + c) * DIN + d];
        #pragma unroll
        for (int n = 0; n < NST; ++n) {
            float hl = hloc[base + (size_t)n * DIN];
            hloc[base + (size_t)n * DIN] = hin[n];
            hin[n] = fmaf(hin[n], __expf(A[n] * s), hl);
        }
    }
}

// S3: per (b,chunk,d) rerun chunk from true entry state; fuse
// y = (sum(h*C) + x*D) * silu(z), write y in-place over xc.
__global__ __launch_bounds__(256)
void scan_part3_kernel(const float* __restrict__ delta, float* __restrict__ xcy,
                       const float* __restrict__ xdbl, const float* __restrict__ z,
                       const float* __restrict__ A_log, const float* __restrict__ Dp,
                       const float* __restrict__ hin_buf)
{
    int d = blockIdx.x * 256 + threadIdx.x;
    int c = blockIdx.y;
    int b = blockIdx.z;
    float A[NST], h[NST];
    size_t base = (size_t)(b * NCH + c) * NST * DIN + d;
    #pragma unroll
    for (int n = 0; n < NST; ++n) {
        A[n] = -__expf(A_log[d * NST + n]);
        h[n] = hin_buf[base + (size_t)n * DIN];
    }
    float Dv = Dp[d];
    int tok = b * LSEQ + c * CHUNK;
    for (int t = 0; t < CHUNK; ++t, ++tok) {
        float dv = delta[(size_t)tok * DIN + d];
        float xv = xcy[(size_t)tok * DIN + d];
        float zv = z[(size_t)tok * DIN + d];
        const float* bc = xdbl + (size_t)tok * 160 + RR;
        float dx = dv * xv;
        float y = 0.f;
        #pragma unroll
        for (int n = 0; n < NST; ++n) {
            h[n] = fmaf(h[n], __expf(dv * A[n]), dx * bc[n]);
            y = fmaf(h[n], bc[NST + n], y);
        }
        y = (y + xv * Dv) * (zv * sigmoidf_(zv));
        xcy[(size_t)tok * DIN + d] = y;
    }
}

extern "C" void kernel_launch(void* const* d_in, const int* in_sizes, int n_in,
                              void* d_out, int out_size, void* d_ws, size_t ws_size,
                              hipStream_t stream)
{
    const float* hidden     = (const float*)d_in[0];  // (2,2048,2048)
    const float* in_proj_w  = (const float*)d_in[1];  // (8192,2048)
    const float* conv_w     = (const float*)d_in[2];  // (4096,4)
    const float* x_proj_w   = (const float*)d_in[3];  // (160,4096)
    const float* dt_proj_w  = (const float*)d_in[4];  // (4096,128)
    const float* dt_bias    = (const float*)d_in[5];  // (4096,)
    const float* A_log      = (const float*)d_in[6];  // (4096,16)
    const float* D_param    = (const float*)d_in[7];  // (4096,)
    const float* out_proj_w = (const float*)d_in[8];  // (2048,4096)
    float* out = (float*)d_out;                       // (2,2048,2048) fp32

    // Workspace: 3 x 67.1 MB + 2.6 MB = 204 MB
    const size_t BIG = (size_t)NTOK * DIN * sizeof(float);   // 67,108,864 B
    char* ws = (char*)d_ws;
    float* xbuf = (float*)(ws);
    float* xc   = (float*)(ws + BIG);
    float* zbuf = (float*)(ws + 2 * BIG);
    float* xdbl = (float*)(ws + 3 * BIG);                    // 2.6 MB
    float* delta = xbuf;                                     // reuse after conv

    // Scan scratch lives in d_out (33.5 MB; fully overwritten by final GEMM):
    // hloc: BB*NCH*NST*DIN = 4,194,304 floats (16.8 MB), ssum: 262,144 floats (1 MB)
    float* hloc = out;
    float* ssum = out + (size_t)BB * NCH * NST * DIN;

    // 1a) x = hidden @ in_proj_w[0:4096]^T        M=4096 N=4096 K=2048
    gemm128_kernel<0><<<dim3(32, 32), 256, 0, stream>>>(hidden, in_proj_w, xbuf,
                                                        2048, 2048, 2048, DIN, nullptr);
    // 1b) z = hidden @ in_proj_w[4096:8192]^T
    gemm128_kernel<0><<<dim3(32, 32), 256, 0, stream>>>(hidden,
                                                        in_proj_w + (size_t)DIN * 2048,
                                                        zbuf, 2048, 2048, 2048, DIN, nullptr);
    // 2) xc = silu(causal_conv(x))
    conv_silu_kernel<<<(NTOK * DIN) / 256, 256, 0, stream>>>(xbuf, conv_w, xc);
    // 3) x_dbl = xc @ x_proj_w^T                  M=4096 N=160 K=4096
    gemm_skinny_kernel<<<dim3(5, 32), 256, 0, stream>>>(xc, x_proj_w, xdbl, 4096, 160);
    // 4) delta = softplus(dt_r @ dt_proj_w^T + bias)   M=4096 N=4096 K=128 (lda=160)
    gemm128_kernel<1><<<dim3(32, 32), 256, 0, stream>>>(xdbl, dt_proj_w, delta,
                                                        128, 160, 128, DIN, dt_bias);
    // 5) chunked selective scan (S1 -> S2 -> S3), y overwrites xc
    scan_part1_kernel<<<dim3(DIN / 256, NCH, BB), 256, 0, stream>>>(delta, xc, xdbl,
                                                                    A_log, hloc, ssum);
    scan_part2_kernel<<<(BB * DIN) / 256, 256, 0, stream>>>(hloc, ssum, A_log);
    scan_part3_kernel<<<dim3(DIN / 256, NCH, BB), 256, 0, stream>>>(delta, xc, xdbl,
                                                                    zbuf, A_log, D_param, hloc);
    // 6) out = y @ out_proj_w^T                   M=4096 N=2048 K=4096
    gemm128_kernel<0><<<dim3(16, 32), 256, 0, stream>>>(xc, out_proj_w, out,
                                                        4096, 4096, 4096, 2048, nullptr);
}

// Round 4
// 1021.860 us; speedup vs baseline: 3.9200x; 3.0385x over previous
//
#include <hip/hip_runtime.h>
#include <math.h>

// Problem constants
#define DIN   4096
#define NST   16
#define RR    128
#define LSEQ  2048
#define NTOK  4096   // B*L
#define BB    2
#define CHUNK 64
#define NCH   (LSEQ / CHUNK)   // 32

typedef __attribute__((ext_vector_type(8))) short short8;
typedef __attribute__((ext_vector_type(4))) float f32x4;

__device__ __forceinline__ float sigmoidf_(float x) { return 1.f / (1.f + __expf(-x)); }
__device__ __forceinline__ float softplusf_(float x) {
    return fmaxf(x, 0.f) + log1pf(__expf(-fabsf(x)));
}
__device__ __forceinline__ unsigned short f2bf_(float f) {
    unsigned u = __float_as_uint(f);
    return (unsigned short)((u + 0x7FFFu + ((u >> 16) & 1u)) >> 16);   // RNE
}
__device__ __forceinline__ void gld_lds16_(const unsigned short* g, unsigned short* l) {
    __builtin_amdgcn_global_load_lds((const __attribute__((address_space(1))) unsigned int*)g,
                                     (__attribute__((address_space(3))) unsigned int*)l,
                                     16, 0, 0);
}

// fp32 -> bf16 (RNE), 8 elements/thread, n8 = n/8 threads
__global__ __launch_bounds__(256)
void f2bf_kernel(const float* __restrict__ src, unsigned short* __restrict__ dst, int n8)
{
    int i = blockIdx.x * 256 + threadIdx.x;
    if (i >= n8) return;
    const float4* s = (const float4*)src + 2 * (size_t)i;
    float4 a = s[0], b = s[1];
    union { unsigned short u[8]; uint4 v; } o;
    o.u[0] = f2bf_(a.x); o.u[1] = f2bf_(a.y); o.u[2] = f2bf_(a.z); o.u[3] = f2bf_(a.w);
    o.u[4] = f2bf_(b.x); o.u[5] = f2bf_(b.y); o.u[6] = f2bf_(b.z); o.u[7] = f2bf_(b.w);
    ((uint4*)dst)[i] = o.v;
}

// ---- bf16 MFMA GEMM (m97 structure) ---------------------------------------
// C[M,N] fp32 = A[M,K] * W[N,K]^T, A/W bf16 row-major (stride K).
// 128x128 tile, BK=32, 256 thr (4 waves in 2x2 of 64x64), 16x16x32 MFMA.
// Staging: global_load_lds width=16, contiguous [row][k] LDS layout (no pad).
__global__ __launch_bounds__(256)
void gemm_mfma_bt(const unsigned short* __restrict__ A, const unsigned short* __restrict__ W,
                  float* __restrict__ C, int K, int ldc)
{
    __shared__ unsigned short As[128 * 32];   // 8 KB
    __shared__ unsigned short Ws[128 * 32];   // 8 KB
    const int tid = threadIdx.x;
    const int bm = blockIdx.y << 7;
    const int bn = blockIdx.x << 7;

    // staging chunks: 512 x 16B per tile, 2 per thread
    const int c0 = tid, c1 = tid + 256;
    const unsigned short* ga0 = A + (size_t)(bm + (c0 >> 2)) * K + (c0 & 3) * 8;
    const unsigned short* ga1 = A + (size_t)(bm + (c1 >> 2)) * K + (c1 & 3) * 8;
    const unsigned short* gw0 = W + (size_t)(bn + (c0 >> 2)) * K + (c0 & 3) * 8;
    const unsigned short* gw1 = W + (size_t)(bn + (c1 >> 2)) * K + (c1 & 3) * 8;
    unsigned short* la0 = &As[c0 * 8];
    unsigned short* la1 = &As[c1 * 8];
    unsigned short* lw0 = &Ws[c0 * 8];
    unsigned short* lw1 = &Ws[c1 * 8];

    const int ln  = tid & 63;
    const int wv  = tid >> 6;
    const int wm  = (wv >> 1) << 6;   // 0 or 64
    const int wn  = (wv & 1) << 6;
    const int m15 = ln & 15;
    const int q   = ln >> 4;          // 0..3

    f32x4 acc[4][4] = {};

    for (int k0 = 0; k0 < K; k0 += 32) {
        __syncthreads();   // previous tile's LDS reads complete
        gld_lds16_(ga0, la0); gld_lds16_(ga1, la1);
        gld_lds16_(gw0, lw0); gld_lds16_(gw1, lw1);
        ga0 += 32; ga1 += 32; gw0 += 32; gw1 += 32;
        __syncthreads();   // staging landed
        short8 af[4], wf[4];
        #pragma unroll
        for (int i = 0; i < 4; ++i)
            af[i] = *(const short8*)&As[(wm + i * 16 + m15) * 32 + q * 8];
        #pragma unroll
        for (int j = 0; j < 4; ++j)
            wf[j] = *(const short8*)&Ws[(wn + j * 16 + m15) * 32 + q * 8];
        #pragma unroll
        for (int i = 0; i < 4; ++i)
            #pragma unroll
            for (int j = 0; j < 4; ++j)
                acc[i][j] = __builtin_amdgcn_mfma_f32_16x16x32_bf16(af[i], wf[j],
                                                                    acc[i][j], 0, 0, 0);
    }

    #pragma unroll
    for (int i = 0; i < 4; ++i)
        #pragma unroll
        for (int j = 0; j < 4; ++j) {
            int col = bn + wn + j * 16 + m15;
            #pragma unroll
            for (int r = 0; r < 4; ++r) {
                int row = bm + wm + i * 16 + q * 4 + r;
                C[(size_t)row * ldc + col] = acc[i][j][r];
            }
        }
}

// fp32 fallback GEMM (used for delta: K=128), 128x128 tile, BK=8.
// EPI==1: C = softplus(C + bias[col])
template<int EPI>
__global__ __launch_bounds__(256)
void gemm128_kernel(const float* __restrict__ A, const float* __restrict__ W,
                    float* __restrict__ C, int K, int lda, int ldw, int ldc,
                    const float* __restrict__ bias)
{
    __shared__ float As[8][128];
    __shared__ float Ws[8][128];
    const int tid = threadIdx.x;
    const int tx = tid & 15;
    const int ty = tid >> 4;
    const int bm = blockIdx.y << 7;
    const int bn = blockIdx.x << 7;
    const int lr = tid >> 1;
    const int lc = (tid & 1) << 2;

    const float* Ap = A + (size_t)(bm + lr) * lda + lc;
    const float* Wp = W + (size_t)(bn + lr) * ldw + lc;

    float acc[8][8] = {};

    for (int k0 = 0; k0 < K; k0 += 8) {
        float4 av = *(const float4*)Ap;
        float4 wv = *(const float4*)Wp;
        Ap += 8; Wp += 8;
        __syncthreads();
        As[lc + 0][lr] = av.x; As[lc + 1][lr] = av.y;
        As[lc + 2][lr] = av.z; As[lc + 3][lr] = av.w;
        Ws[lc + 0][lr] = wv.x; Ws[lc + 1][lr] = wv.y;
        Ws[lc + 2][lr] = wv.z; Ws[lc + 3][lr] = wv.w;
        __syncthreads();
        #pragma unroll
        for (int kk = 0; kk < 8; ++kk) {
            float4 a0 = *(const float4*)&As[kk][ty * 4];
            float4 a1 = *(const float4*)&As[kk][64 + ty * 4];
            float4 w0 = *(const float4*)&Ws[kk][tx * 4];
            float4 w1 = *(const float4*)&Ws[kk][64 + tx * 4];
            float a[8] = {a0.x, a0.y, a0.z, a0.w, a1.x, a1.y, a1.z, a1.w};
            float w[8] = {w0.x, w0.y, w0.z, w0.w, w1.x, w1.y, w1.z, w1.w};
            #pragma unroll
            for (int i = 0; i < 8; ++i)
                #pragma unroll
                for (int j = 0; j < 8; ++j)
                    acc[i][j] = fmaf(a[i], w[j], acc[i][j]);
        }
    }

    #pragma unroll
    for (int i = 0; i < 8; ++i) {
        int r = bm + ((i < 4) ? (ty * 4 + i) : (64 + ty * 4 + i - 4));
        #pragma unroll
        for (int jh = 0; jh < 2; ++jh) {
            int c = bn + jh * 64 + tx * 4;
            float4 v;
            v.x = acc[i][jh * 4 + 0];
            v.y = acc[i][jh * 4 + 1];
            v.z = acc[i][jh * 4 + 2];
            v.w = acc[i][jh * 4 + 3];
            if (EPI == 1) {
                v.x = softplusf_(v.x + bias[c + 0]);
                v.y = softplusf_(v.y + bias[c + 1]);
                v.z = softplusf_(v.z + bias[c + 2]);
                v.w = softplusf_(v.w + bias[c + 3]);
            }
            *(float4*)&C[(size_t)r * ldc + c] = v;
        }
    }
}

// Tall-skinny GEMM for x_proj: C[M,160] = A[M,K] * W[160,K]^T
__global__ __launch_bounds__(256)
void gemm_skinny_kernel(const float* __restrict__ A, const float* __restrict__ W,
                        float* __restrict__ C, int K, int ldc)
{
    __shared__ float As[16][132];
    __shared__ float Ws[16][36];
    const int tid = threadIdx.x;
    const int tx = tid & 15;
    const int ty = tid >> 4;
    const int bm = blockIdx.y << 7;
    const int bn = blockIdx.x << 5;
    const int ar = tid >> 2;
    const int ac = (tid & 3) << 2;

    float acc[8][2] = {};

    for (int k0 = 0; k0 < K; k0 += 16) {
        float4 v0 = *(const float4*)&A[(size_t)(bm + ar) * K + k0 + ac];
        float4 v1 = *(const float4*)&A[(size_t)(bm + 64 + ar) * K + k0 + ac];
        float4 wv;
        if (tid < 128) wv = *(const float4*)&W[(size_t)(bn + (tid >> 2)) * K + k0 + ac];
        __syncthreads();
        As[ac + 0][ar] = v0.x; As[ac + 1][ar] = v0.y;
        As[ac + 2][ar] = v0.z; As[ac + 3][ar] = v0.w;
        As[ac + 0][64 + ar] = v1.x; As[ac + 1][64 + ar] = v1.y;
        As[ac + 2][64 + ar] = v1.z; As[ac + 3][64 + ar] = v1.w;
        if (tid < 128) {
            int wr = tid >> 2;
            Ws[ac + 0][wr] = wv.x; Ws[ac + 1][wr] = wv.y;
            Ws[ac + 2][wr] = wv.z; Ws[ac + 3][wr] = wv.w;
        }
        __syncthreads();
        #pragma unroll
        for (int kk = 0; kk < 16; ++kk) {
            float4 a0 = *(const float4*)&As[kk][ty * 4];
            float4 a1 = *(const float4*)&As[kk][64 + ty * 4];
            float2 w2 = *(const float2*)&Ws[kk][tx * 2];
            float a[8] = {a0.x, a0.y, a0.z, a0.w, a1.x, a1.y, a1.z, a1.w};
            #pragma unroll
            for (int i = 0; i < 8; ++i) {
                acc[i][0] = fmaf(a[i], w2.x, acc[i][0]);
                acc[i][1] = fmaf(a[i], w2.y, acc[i][1]);
            }
        }
    }

    #pragma unroll
    for (int i = 0; i < 8; ++i) {
        int r = bm + ((i < 4) ? (ty * 4 + i) : (64 + ty * 4 + i - 4));
        int c = bn + tx * 2;
        *(float2*)&C[(size_t)r * ldc + c] = make_float2(acc[i][0], acc[i][1]);
    }
}

// Causal depthwise conv (K=4) + SiLU.
__global__ __launch_bounds__(256)
void conv_silu_kernel(const float* __restrict__ x, const float* __restrict__ cw,
                      float* __restrict__ xc)
{
    int idx = blockIdx.x * 256 + threadIdx.x;
    int d = idx & (DIN - 1);
    int tok = idx >> 12;
    int t = tok & (LSEQ - 1);
    float w0 = cw[d * 4 + 0], w1 = cw[d * 4 + 1];
    float w2 = cw[d * 4 + 2], w3 = cw[d * 4 + 3];
    const float* xp = x + (size_t)tok * DIN + d;
    float acc = w3 * xp[0];
    if (t >= 1) acc = fmaf(w2, xp[-DIN], acc);
    if (t >= 2) acc = fmaf(w1, xp[-2 * DIN], acc);
    if (t >= 3) acc = fmaf(w0, xp[-3 * DIN], acc);
    xc[idx] = acc * sigmoidf_(acc);
}

// ---- Chunked parallel selective scan --------------------------------------
__global__ __launch_bounds__(256)
void scan_part1_kernel(const float* __restrict__ delta, const float* __restrict__ xc,
                       const float* __restrict__ xdbl, const float* __restrict__ A_log,
                       float* __restrict__ hloc, float* __restrict__ ssum)
{
    int d = blockIdx.x * 256 + threadIdx.x;
    int c = blockIdx.y;
    int b = blockIdx.z;
    float A[NST], h[NST];
    #pragma unroll
    for (int n = 0; n < NST; ++n) {
        A[n] = -__expf(A_log[d * NST + n]);
        h[n] = 0.f;
    }
    float s = 0.f;
    int tok = b * LSEQ + c * CHUNK;
    for (int t = 0; t < CHUNK; ++t, ++tok) {
        float dv = delta[(size_t)tok * DIN + d];
        float xv = xc[(size_t)tok * DIN + d];
        const float* bc = xdbl + (size_t)tok * 160 + RR;
        float dx = dv * xv;
        s += dv;
        #pragma unroll
        for (int n = 0; n < NST; ++n)
            h[n] = fmaf(h[n], __expf(dv * A[n]), dx * bc[n]);
    }
    size_t base = (size_t)(b * NCH + c) * NST * DIN + d;
    #pragma unroll
    for (int n = 0; n < NST; ++n) hloc[base + (size_t)n * DIN] = h[n];
    ssum[(size_t)(b * NCH + c) * DIN + d] = s;
}

__global__ __launch_bounds__(256)
void scan_part2_kernel(float* __restrict__ hloc, const float* __restrict__ ssum,
                       const float* __restrict__ A_log)
{
    int idx = blockIdx.x * 256 + threadIdx.x;   // over BB*DIN
    int b = idx >> 12;
    int d = idx & (DIN - 1);
    float A[NST], hin[NST];
    #pragma unroll
    for (int n = 0; n < NST; ++n) {
        A[n] = -__expf(A_log[d * NST + n]);
        hin[n] = 0.f;
    }
    for (int c = 0; c < NCH; ++c) {
        size_t base = (size_t)(b * NCH + c) * NST * DIN + d;
        float s = ssum[(size_t)(b * NCH + c) * DIN + d];
        #pragma unroll
        for (int n = 0; n < NST; ++n) {
            float hl = hloc[base + (size_t)n * DIN];
            hloc[base + (size_t)n * DIN] = hin[n];
            hin[n] = fmaf(hin[n], __expf(A[n] * s), hl);
        }
    }
}

__global__ __launch_bounds__(256)
void scan_part3_kernel(const float* __restrict__ delta, float* __restrict__ xcy,
                       const float* __restrict__ xdbl, const float* __restrict__ z,
                       const float* __restrict__ A_log, const float* __restrict__ Dp,
                       const float* __restrict__ hin_buf)
{
    int d = blockIdx.x * 256 + threadIdx.x;
    int c = blockIdx.y;
    int b = blockIdx.z;
    float A[NST], h[NST];
    size_t base = (size_t)(b * NCH + c) * NST * DIN + d;
    #pragma unroll
    for (int n = 0; n < NST; ++n) {
        A[n] = -__expf(A_log[d * NST + n]);
        h[n] = hin_buf[base + (size_t)n * DIN];
    }
    float Dv = Dp[d];
    int tok = b * LSEQ + c * CHUNK;
    for (int t = 0; t < CHUNK; ++t, ++tok) {
        float dv = delta[(size_t)tok * DIN + d];
        float xv = xcy[(size_t)tok * DIN + d];
        float zv = z[(size_t)tok * DIN + d];
        const float* bc = xdbl + (size_t)tok * 160 + RR;
        float dx = dv * xv;
        float y = 0.f;
        #pragma unroll
        for (int n = 0; n < NST; ++n) {
            h[n] = fmaf(h[n], __expf(dv * A[n]), dx * bc[n]);
            y = fmaf(h[n], bc[NST + n], y);
        }
        y = (y + xv * Dv) * (zv * sigmoidf_(zv));
        xcy[(size_t)tok * DIN + d] = y;
    }
}

extern "C" void kernel_launch(void* const* d_in, const int* in_sizes, int n_in,
                              void* d_out, int out_size, void* d_ws, size_t ws_size,
                              hipStream_t stream)
{
    const float* hidden     = (const float*)d_in[0];  // (2,2048,2048)
    const float* in_proj_w  = (const float*)d_in[1];  // (8192,2048)
    const float* conv_w     = (const float*)d_in[2];  // (4096,4)
    const float* x_proj_w   = (const float*)d_in[3];  // (160,4096)
    const float* dt_proj_w  = (const float*)d_in[4];  // (4096,128)
    const float* dt_bias    = (const float*)d_in[5];  // (4096,)
    const float* A_log      = (const float*)d_in[6];  // (4096,16)
    const float* D_param    = (const float*)d_in[7];  // (4096,)
    const float* out_proj_w = (const float*)d_in[8];  // (2048,4096)
    float* out = (float*)d_out;                       // (2,2048,2048) fp32

    // Workspace: 3 x 67.1 MB + 2.6 MB = 204 MB (known-safe footprint)
    const size_t BIG = (size_t)NTOK * DIN * sizeof(float);   // 67,108,864 B
    char* ws = (char*)d_ws;
    float* xbuf = (float*)(ws);                              // x -> delta -> y_bf
    float* xc   = (float*)(ws + BIG);                        // w_in_bf -> xc/y
    float* zbuf = (float*)(ws + 2 * BIG);                    // z -> w_out_bf
    float* xdbl = (float*)(ws + 3 * BIG);                    // 2.6 MB
    float* delta = xbuf;

    // bf16 staging buffers in dead regions:
    unsigned short* w_in_bf  = (unsigned short*)xc;          // 33.5 MB, dies at conv
    unsigned short* hid_bf   = (unsigned short*)out;         // 16.8 MB in d_out, dies after G1
    unsigned short* y_bf     = (unsigned short*)xbuf;        // after delta is dead
    unsigned short* w_out_bf = (unsigned short*)zbuf;        // after z is dead

    // scan scratch in d_out (hid_bf dead by then; overwritten by final GEMM):
    float* hloc = out;                                       // 16.8 MB
    float* ssum = out + (size_t)BB * NCH * NST * DIN;        // 1 MB

    // 0) fp32 -> bf16 conversions for GEMM1
    f2bf_kernel<<<8192, 256, 0, stream>>>(in_proj_w, w_in_bf, (2 * DIN * 2048) / 8);
    f2bf_kernel<<<4096, 256, 0, stream>>>(hidden, hid_bf, (NTOK * 2048) / 8);
    // 1a) x = hidden @ in_proj_w[0:4096]^T   (bf16 MFMA)  M=4096 N=4096 K=2048
    gemm_mfma_bt<<<dim3(32, 32), 256, 0, stream>>>(hid_bf, w_in_bf, xbuf, 2048, DIN);
    // 1b) z = hidden @ in_proj_w[4096:8192]^T
    gemm_mfma_bt<<<dim3(32, 32), 256, 0, stream>>>(hid_bf, w_in_bf + (size_t)DIN * 2048,
                                                   zbuf, 2048, DIN);
    // 2) xc = silu(causal_conv(x))   (overwrites w_in_bf region - now dead)
    conv_silu_kernel<<<(NTOK * DIN) / 256, 256, 0, stream>>>(xbuf, conv_w, xc);
    // 3) x_dbl = xc @ x_proj_w^T             M=4096 N=160 K=4096 (fp32)
    gemm_skinny_kernel<<<dim3(5, 32), 256, 0, stream>>>(xc, x_proj_w, xdbl, 4096, 160);
    // 4) delta = softplus(dt_r @ dt_proj_w^T + bias)  K=128 (fp32, overwrites x)
    gemm128_kernel<1><<<dim3(32, 32), 256, 0, stream>>>(xdbl, dt_proj_w, delta,
                                                        128, 160, 128, DIN, dt_bias);
    // 5) chunked selective scan, y overwrites xc
    scan_part1_kernel<<<dim3(DIN / 256, NCH, BB), 256, 0, stream>>>(delta, xc, xdbl,
                                                                    A_log, hloc, ssum);
    scan_part2_kernel<<<(BB * DIN) / 256, 256, 0, stream>>>(hloc, ssum, A_log);
    scan_part3_kernel<<<dim3(DIN / 256, NCH, BB), 256, 0, stream>>>(delta, xc, xdbl,
                                                                    zbuf, A_log, D_param, hloc);
    // 5c) y -> bf16 (into dead delta region); out_proj -> bf16 (into dead z region)
    f2bf_kernel<<<8192, 256, 0, stream>>>(xc, y_bf, (NTOK * DIN) / 8);
    f2bf_kernel<<<4096, 256, 0, stream>>>(out_proj_w, w_out_bf, (2048 * DIN) / 8);
    // 6) out = y @ out_proj_w^T  (bf16 MFMA)  M=4096 N=2048 K=4096
    gemm_mfma_bt<<<dim3(16, 32), 256, 0, stream>>>(y_bf, w_out_bf, out, 4096, 2048);
}

// Round 5
// 871.681 us; speedup vs baseline: 4.5954x; 1.1723x over previous
//
#include <hip/hip_runtime.h>
#include <math.h>

// Problem constants
#define DIN   4096
#define NST   16
#define RR    128
#define LSEQ  2048
#define NTOK  4096   // B*L
#define BB    2
#define CHUNK 64
#define NCH   (LSEQ / CHUNK)   // 32
#define KSPL  8                // k-split for skinny GEMM
#define KC    (DIN / KSPL)     // 512

typedef __attribute__((ext_vector_type(8))) short short8;
typedef __attribute__((ext_vector_type(4))) float f32x4;

__device__ __forceinline__ float sigmoidf_(float x) { return 1.f / (1.f + __expf(-x)); }
__device__ __forceinline__ float softplusf_(float x) {
    return fmaxf(x, 0.f) + log1pf(__expf(-fabsf(x)));
}
__device__ __forceinline__ unsigned short f2bf_(float f) {
    unsigned u = __float_as_uint(f);
    return (unsigned short)((u + 0x7FFFu + ((u >> 16) & 1u)) >> 16);   // RNE
}
__device__ __forceinline__ void gld_lds16_(const unsigned short* g, unsigned short* l) {
    __builtin_amdgcn_global_load_lds((const __attribute__((address_space(1))) unsigned int*)g,
                                     (__attribute__((address_space(3))) unsigned int*)l,
                                     16, 0, 0);
}

// fp32 -> bf16 (RNE), 8 elements/thread
__global__ __launch_bounds__(256)
void f2bf_kernel(const float* __restrict__ src, unsigned short* __restrict__ dst, int n8)
{
    int i = blockIdx.x * 256 + threadIdx.x;
    if (i >= n8) return;
    const float4* s = (const float4*)src + 2 * (size_t)i;
    float4 a = s[0], b = s[1];
    union { unsigned short u[8]; uint4 v; } o;
    o.u[0] = f2bf_(a.x); o.u[1] = f2bf_(a.y); o.u[2] = f2bf_(a.z); o.u[3] = f2bf_(a.w);
    o.u[4] = f2bf_(b.x); o.u[5] = f2bf_(b.y); o.u[6] = f2bf_(b.z); o.u[7] = f2bf_(b.w);
    ((uint4*)dst)[i] = o.v;
}

// ---- bf16 MFMA GEMM (m97 structure) ---------------------------------------
__global__ __launch_bounds__(256)
void gemm_mfma_bt(const unsigned short* __restrict__ A, const unsigned short* __restrict__ W,
                  float* __restrict__ C, int K, int ldc)
{
    __shared__ unsigned short As[128 * 32];
    __shared__ unsigned short Ws[128 * 32];
    const int tid = threadIdx.x;
    const int bm = blockIdx.y << 7;
    const int bn = blockIdx.x << 7;

    const int c0 = tid, c1 = tid + 256;
    const unsigned short* ga0 = A + (size_t)(bm + (c0 >> 2)) * K + (c0 & 3) * 8;
    const unsigned short* ga1 = A + (size_t)(bm + (c1 >> 2)) * K + (c1 & 3) * 8;
    const unsigned short* gw0 = W + (size_t)(bn + (c0 >> 2)) * K + (c0 & 3) * 8;
    const unsigned short* gw1 = W + (size_t)(bn + (c1 >> 2)) * K + (c1 & 3) * 8;
    unsigned short* la0 = &As[c0 * 8];
    unsigned short* la1 = &As[c1 * 8];
    unsigned short* lw0 = &Ws[c0 * 8];
    unsigned short* lw1 = &Ws[c1 * 8];

    const int ln  = tid & 63;
    const int wv  = tid >> 6;
    const int wm  = (wv >> 1) << 6;
    const int wn  = (wv & 1) << 6;
    const int m15 = ln & 15;
    const int q   = ln >> 4;

    f32x4 acc[4][4] = {};

    for (int k0 = 0; k0 < K; k0 += 32) {
        __syncthreads();
        gld_lds16_(ga0, la0); gld_lds16_(ga1, la1);
        gld_lds16_(gw0, lw0); gld_lds16_(gw1, lw1);
        ga0 += 32; ga1 += 32; gw0 += 32; gw1 += 32;
        __syncthreads();
        short8 af[4], wf[4];
        #pragma unroll
        for (int i = 0; i < 4; ++i)
            af[i] = *(const short8*)&As[(wm + i * 16 + m15) * 32 + q * 8];
        #pragma unroll
        for (int j = 0; j < 4; ++j)
            wf[j] = *(const short8*)&Ws[(wn + j * 16 + m15) * 32 + q * 8];
        #pragma unroll
        for (int i = 0; i < 4; ++i)
            #pragma unroll
            for (int j = 0; j < 4; ++j)
                acc[i][j] = __builtin_amdgcn_mfma_f32_16x16x32_bf16(af[i], wf[j],
                                                                    acc[i][j], 0, 0, 0);
    }

    #pragma unroll
    for (int i = 0; i < 4; ++i)
        #pragma unroll
        for (int j = 0; j < 4; ++j) {
            int col = bn + wn + j * 16 + m15;
            #pragma unroll
            for (int r = 0; r < 4; ++r) {
                int row = bm + wm + i * 16 + q * 4 + r;
                C[(size_t)row * ldc + col] = acc[i][j][r];
            }
        }
}

// fp32 GEMM (used for delta: K=128), 128x128 tile, BK=8.
template<int EPI>
__global__ __launch_bounds__(256)
void gemm128_kernel(const float* __restrict__ A, const float* __restrict__ W,
                    float* __restrict__ C, int K, int lda, int ldw, int ldc,
                    const float* __restrict__ bias)
{
    __shared__ float As[8][128];
    __shared__ float Ws[8][128];
    const int tid = threadIdx.x;
    const int tx = tid & 15;
    const int ty = tid >> 4;
    const int bm = blockIdx.y << 7;
    const int bn = blockIdx.x << 7;
    const int lr = tid >> 1;
    const int lc = (tid & 1) << 2;

    const float* Ap = A + (size_t)(bm + lr) * lda + lc;
    const float* Wp = W + (size_t)(bn + lr) * ldw + lc;

    float acc[8][8] = {};

    for (int k0 = 0; k0 < K; k0 += 8) {
        float4 av = *(const float4*)Ap;
        float4 wv = *(const float4*)Wp;
        Ap += 8; Wp += 8;
        __syncthreads();
        As[lc + 0][lr] = av.x; As[lc + 1][lr] = av.y;
        As[lc + 2][lr] = av.z; As[lc + 3][lr] = av.w;
        Ws[lc + 0][lr] = wv.x; Ws[lc + 1][lr] = wv.y;
        Ws[lc + 2][lr] = wv.z; Ws[lc + 3][lr] = wv.w;
        __syncthreads();
        #pragma unroll
        for (int kk = 0; kk < 8; ++kk) {
            float4 a0 = *(const float4*)&As[kk][ty * 4];
            float4 a1 = *(const float4*)&As[kk][64 + ty * 4];
            float4 w0 = *(const float4*)&Ws[kk][tx * 4];
            float4 w1 = *(const float4*)&Ws[kk][64 + tx * 4];
            float a[8] = {a0.x, a0.y, a0.z, a0.w, a1.x, a1.y, a1.z, a1.w};
            float w[8] = {w0.x, w0.y, w0.z, w0.w, w1.x, w1.y, w1.z, w1.w};
            #pragma unroll
            for (int i = 0; i < 8; ++i)
                #pragma unroll
                for (int j = 0; j < 8; ++j)
                    acc[i][j] = fmaf(a[i], w[j], acc[i][j]);
        }
    }

    #pragma unroll
    for (int i = 0; i < 8; ++i) {
        int r = bm + ((i < 4) ? (ty * 4 + i) : (64 + ty * 4 + i - 4));
        #pragma unroll
        for (int jh = 0; jh < 2; ++jh) {
            int c = bn + jh * 64 + tx * 4;
            float4 v;
            v.x = acc[i][jh * 4 + 0];
            v.y = acc[i][jh * 4 + 1];
            v.z = acc[i][jh * 4 + 2];
            v.w = acc[i][jh * 4 + 3];
            if (EPI == 1) {
                v.x = softplusf_(v.x + bias[c + 0]);
                v.y = softplusf_(v.y + bias[c + 1]);
                v.z = softplusf_(v.z + bias[c + 2]);
                v.w = softplusf_(v.w + bias[c + 3]);
            }
            *(float4*)&C[(size_t)r * ldc + c] = v;
        }
    }
}

// ---- K-split skinny GEMM: partial[kspl][M][160] = A[M, kc] * W[160, kc]^T --
// Grid (M/64, KSPL). 64x160 tile per block, BK=16, 256 thr, 4x10 acc/thread.
__global__ __launch_bounds__(256)
void gemm_kspl_kernel(const float* __restrict__ A, const float* __restrict__ W,
                      float* __restrict__ partial)
{
    __shared__ float As[16][66];    // stride 66: float2-aligned, bank-spread
    __shared__ float Ws[16][162];
    const int tid = threadIdx.x;
    const int tx = tid & 15;        // col group: cols tx*10 .. tx*10+9
    const int ty = tid >> 4;        // row group: rows ty*4 .. ty*4+3
    const int bm = blockIdx.x << 6;
    const int k0 = blockIdx.y * KC;

    float acc[4][10] = {};

    for (int kt = 0; kt < KC; kt += 16) {
        // stage A: 64 rows x 16 k (2 float2/thread)
        float2 a2[2];
        #pragma unroll
        for (int i = 0; i < 2; ++i) {
            int idx = tid + 256 * i;
            int row = idx >> 3, kofs = (idx & 7) * 2;
            a2[i] = *(const float2*)&A[(size_t)(bm + row) * DIN + k0 + kt + kofs];
        }
        // stage W: 160 rows x 16 k (5 float2/thread)
        float2 w2[5];
        #pragma unroll
        for (int i = 0; i < 5; ++i) {
            int idx = tid + 256 * i;
            int wrow = idx >> 3, wk = (idx & 7) * 2;
            w2[i] = *(const float2*)&W[(size_t)wrow * DIN + k0 + kt + wk];
        }
        __syncthreads();
        #pragma unroll
        for (int i = 0; i < 2; ++i) {
            int idx = tid + 256 * i;
            int row = idx >> 3, kofs = (idx & 7) * 2;
            As[kofs][row] = a2[i].x; As[kofs + 1][row] = a2[i].y;
        }
        #pragma unroll
        for (int i = 0; i < 5; ++i) {
            int idx = tid + 256 * i;
            int wrow = idx >> 3, wk = (idx & 7) * 2;
            Ws[wk][wrow] = w2[i].x; Ws[wk + 1][wrow] = w2[i].y;
        }
        __syncthreads();
        #pragma unroll
        for (int kk = 0; kk < 16; ++kk) {
            float2 av0 = *(const float2*)&As[kk][ty * 4];
            float2 av1 = *(const float2*)&As[kk][ty * 4 + 2];
            float a[4] = {av0.x, av0.y, av1.x, av1.y};
            float w[10];
            #pragma unroll
            for (int j = 0; j < 5; ++j) {
                float2 wv = *(const float2*)&Ws[kk][tx * 10 + 2 * j];
                w[2 * j] = wv.x; w[2 * j + 1] = wv.y;
            }
            #pragma unroll
            for (int i = 0; i < 4; ++i)
                #pragma unroll
                for (int j = 0; j < 10; ++j)
                    acc[i][j] = fmaf(a[i], w[j], acc[i][j]);
        }
        __syncthreads();
    }

    float* po = partial + (size_t)blockIdx.y * NTOK * 160;
    #pragma unroll
    for (int i = 0; i < 4; ++i) {
        int r = bm + ty * 4 + i;
        #pragma unroll
        for (int j = 0; j < 5; ++j)
            *(float2*)&po[(size_t)r * 160 + tx * 10 + 2 * j] =
                make_float2(acc[i][2 * j], acc[i][2 * j + 1]);
    }
}

// sum KSPL partials -> xdbl
__global__ __launch_bounds__(256)
void kspl_reduce_kernel(const float* __restrict__ partial, float* __restrict__ xdbl)
{
    int idx = blockIdx.x * 256 + threadIdx.x;   // over NTOK*160
    float s = 0.f;
    #pragma unroll
    for (int k = 0; k < KSPL; ++k)
        s += partial[(size_t)k * NTOK * 160 + idx];
    xdbl[idx] = s;
}

// Causal depthwise conv (K=4) + SiLU.
__global__ __launch_bounds__(256)
void conv_silu_kernel(const float* __restrict__ x, const float* __restrict__ cw,
                      float* __restrict__ xc)
{
    int idx = blockIdx.x * 256 + threadIdx.x;
    int d = idx & (DIN - 1);
    int tok = idx >> 12;
    int t = tok & (LSEQ - 1);
    float w0 = cw[d * 4 + 0], w1 = cw[d * 4 + 1];
    float w2 = cw[d * 4 + 2], w3 = cw[d * 4 + 3];
    const float* xp = x + (size_t)tok * DIN + d;
    float acc = w3 * xp[0];
    if (t >= 1) acc = fmaf(w2, xp[-DIN], acc);
    if (t >= 2) acc = fmaf(w1, xp[-2 * DIN], acc);
    if (t >= 3) acc = fmaf(w0, xp[-3 * DIN], acc);
    xc[idx] = acc * sigmoidf_(acc);
}

// ---- Chunked parallel selective scan --------------------------------------
__global__ __launch_bounds__(256)
void scan_part1_kernel(const float* __restrict__ delta, const float* __restrict__ xc,
                       const float* __restrict__ xdbl, const float* __restrict__ A_log,
                       float* __restrict__ hloc, float* __restrict__ ssum)
{
    int d = blockIdx.x * 256 + threadIdx.x;
    int c = blockIdx.y;
    int b = blockIdx.z;
    float A[NST], h[NST];
    #pragma unroll
    for (int n = 0; n < NST; ++n) {
        A[n] = -__expf(A_log[d * NST + n]);
        h[n] = 0.f;
    }
    float s = 0.f;
    int tok = b * LSEQ + c * CHUNK;
    for (int t = 0; t < CHUNK; ++t, ++tok) {
        float dv = delta[(size_t)tok * DIN + d];
        float xv = xc[(size_t)tok * DIN + d];
        const float* bc = xdbl + (size_t)tok * 160 + RR;
        float dx = dv * xv;
        s += dv;
        #pragma unroll
        for (int n = 0; n < NST; ++n)
            h[n] = fmaf(h[n], __expf(dv * A[n]), dx * bc[n]);
    }
    size_t base = (size_t)(b * NCH + c) * NST * DIN + d;
    #pragma unroll
    for (int n = 0; n < NST; ++n) hloc[base + (size_t)n * DIN] = h[n];
    ssum[(size_t)(b * NCH + c) * DIN + d] = s;
}

__global__ __launch_bounds__(256)
void scan_part2_kernel(float* __restrict__ hloc, const float* __restrict__ ssum,
                       const float* __restrict__ A_log)
{
    int idx = blockIdx.x * 256 + threadIdx.x;
    int b = idx >> 12;
    int d = idx & (DIN - 1);
    float A[NST], hin[NST];
    #pragma unroll
    for (int n = 0; n < NST; ++n) {
        A[n] = -__expf(A_log[d * NST + n]);
        hin[n] = 0.f;
    }
    for (int c = 0; c < NCH; ++c) {
        size_t base = (size_t)(b * NCH + c) * NST * DIN + d;
        float s = ssum[(size_t)(b * NCH + c) * DIN + d];
        #pragma unroll
        for (int n = 0; n < NST; ++n) {
            float hl = hloc[base + (size_t)n * DIN];
            hloc[base + (size_t)n * DIN] = hin[n];
            hin[n] = fmaf(hin[n], __expf(A[n] * s), hl);
        }
    }
}

__global__ __launch_bounds__(256)
void scan_part3_kernel(const float* __restrict__ delta, float* __restrict__ xcy,
                       const float* __restrict__ xdbl, const float* __restrict__ z,
                       const float* __restrict__ A_log, const float* __restrict__ Dp,
                       const float* __restrict__ hin_buf)
{
    int d = blockIdx.x * 256 + threadIdx.x;
    int c = blockIdx.y;
    int b = blockIdx.z;
    float A[NST], h[NST];
    size_t base = (size_t)(b * NCH + c) * NST * DIN + d;
    #pragma unroll
    for (int n = 0; n < NST; ++n) {
        A[n] = -__expf(A_log[d * NST + n]);
        h[n] = hin_buf[base + (size_t)n * DIN];
    }
    float Dv = Dp[d];
    int tok = b * LSEQ + c * CHUNK;
    for (int t = 0; t < CHUNK; ++t, ++tok) {
        float dv = delta[(size_t)tok * DIN + d];
        float xv = xcy[(size_t)tok * DIN + d];
        float zv = z[(size_t)tok * DIN + d];
        const float* bc = xdbl + (size_t)tok * 160 + RR;
        float dx = dv * xv;
        float y = 0.f;
        #pragma unroll
        for (int n = 0; n < NST; ++n) {
            h[n] = fmaf(h[n], __expf(dv * A[n]), dx * bc[n]);
            y = fmaf(h[n], bc[NST + n], y);
        }
        y = (y + xv * Dv) * (zv * sigmoidf_(zv));
        xcy[(size_t)tok * DIN + d] = y;
    }
}

extern "C" void kernel_launch(void* const* d_in, const int* in_sizes, int n_in,
                              void* d_out, int out_size, void* d_ws, size_t ws_size,
                              hipStream_t stream)
{
    const float* hidden     = (const float*)d_in[0];
    const float* in_proj_w  = (const float*)d_in[1];
    const float* conv_w     = (const float*)d_in[2];
    const float* x_proj_w   = (const float*)d_in[3];
    const float* dt_proj_w  = (const float*)d_in[4];
    const float* dt_bias    = (const float*)d_in[5];
    const float* A_log      = (const float*)d_in[6];
    const float* D_param    = (const float*)d_in[7];
    const float* out_proj_w = (const float*)d_in[8];
    float* out = (float*)d_out;

    // Workspace: 3 x 67.1 MB + 2.6 MB = 204 MB (known-safe footprint)
    const size_t BIG = (size_t)NTOK * DIN * sizeof(float);
    char* ws = (char*)d_ws;
    float* xbuf = (float*)(ws);                              // x -> delta -> y_bf
    float* xc   = (float*)(ws + BIG);                        // w_in_bf -> xc/y
    float* zbuf = (float*)(ws + 2 * BIG);                    // z -> w_out_bf
    float* xdbl = (float*)(ws + 3 * BIG);                    // 2.6 MB
    float* delta = xbuf;

    // bf16 staging buffers in dead regions:
    unsigned short* w_in_bf  = (unsigned short*)xc;          // dies at conv
    unsigned short* hid_bf   = (unsigned short*)out;         // dies after G1
    unsigned short* y_bf     = (unsigned short*)xbuf;        // after delta dead
    unsigned short* w_out_bf = (unsigned short*)zbuf;        // after z dead

    // d_out scratch (33.5 MB), time-multiplexed:
    //   hid_bf (16.8 MB, steps 0-1) -> kspl partial (21 MB, step 3)
    //   -> hloc+ssum (17.8 MB, step 5) -> final GEMM output (step 6)
    float* xpart = out;                                      // 21 MB
    float* hloc  = out;
    float* ssum  = out + (size_t)BB * NCH * NST * DIN;

    // 0) fp32 -> bf16 for GEMM1
    f2bf_kernel<<<8192, 256, 0, stream>>>(in_proj_w, w_in_bf, (2 * DIN * 2048) / 8);
    f2bf_kernel<<<4096, 256, 0, stream>>>(hidden, hid_bf, (NTOK * 2048) / 8);
    // 1) x / z = hidden @ in_proj_w^T (bf16 MFMA)
    gemm_mfma_bt<<<dim3(32, 32), 256, 0, stream>>>(hid_bf, w_in_bf, xbuf, 2048, DIN);
    gemm_mfma_bt<<<dim3(32, 32), 256, 0, stream>>>(hid_bf, w_in_bf + (size_t)DIN * 2048,
                                                   zbuf, 2048, DIN);
    // 2) xc = silu(causal_conv(x))
    conv_silu_kernel<<<(NTOK * DIN) / 256, 256, 0, stream>>>(xbuf, conv_w, xc);
    // 3) x_dbl = xc @ x_proj_w^T  (K-split fp32 + reduce)
    gemm_kspl_kernel<<<dim3(NTOK / 64, KSPL), 256, 0, stream>>>(xc, x_proj_w, xpart);
    kspl_reduce_kernel<<<(NTOK * 160) / 256, 256, 0, stream>>>(xpart, xdbl);
    // 4) delta = softplus(dt_r @ dt_proj_w^T + bias)  (fp32, K=128)
    gemm128_kernel<1><<<dim3(32, 32), 256, 0, stream>>>(xdbl, dt_proj_w, delta,
                                                        128, 160, 128, DIN, dt_bias);
    // 5) chunked selective scan
    scan_part1_kernel<<<dim3(DIN / 256, NCH, BB), 256, 0, stream>>>(delta, xc, xdbl,
                                                                    A_log, hloc, ssum);
    scan_part2_kernel<<<(BB * DIN) / 256, 256, 0, stream>>>(hloc, ssum, A_log);
    scan_part3_kernel<<<dim3(DIN / 256, NCH, BB), 256, 0, stream>>>(delta, xc, xdbl,
                                                                    zbuf, A_log, D_param, hloc);
    // 5c) convert for final GEMM
    f2bf_kernel<<<8192, 256, 0, stream>>>(xc, y_bf, (NTOK * DIN) / 8);
    f2bf_kernel<<<4096, 256, 0, stream>>>(out_proj_w, w_out_bf, (2048 * DIN) / 8);
    // 6) out = y @ out_proj_w^T (bf16 MFMA)
    gemm_mfma_bt<<<dim3(16, 32), 256, 0, stream>>>(y_bf, w_out_bf, out, 4096, 2048);
}

// Round 6
// 816.549 us; speedup vs baseline: 4.9056x; 1.0675x over previous
//
#include <hip/hip_runtime.h>
#include <math.h>

// Problem constants
#define DIN   4096
#define NST   16
#define RR    128
#define LSEQ  2048
#define NTOK  4096   // B*L
#define BB    2
#define CHUNK 64
#define NCH   (LSEQ / CHUNK)   // 32
#define KSPL  8                // k-split for skinny GEMM
#define KC    (DIN / KSPL)     // 512

typedef __attribute__((ext_vector_type(8))) short short8;
typedef __attribute__((ext_vector_type(4))) float f32x4;

__device__ __forceinline__ float sigmoidf_(float x) { return 1.f / (1.f + __expf(-x)); }
__device__ __forceinline__ float softplusf_(float x) {
    return fmaxf(x, 0.f) + log1pf(__expf(-fabsf(x)));
}
__device__ __forceinline__ unsigned short f2bf_(float f) {
    unsigned u = __float_as_uint(f);
    return (unsigned short)((u + 0x7FFFu + ((u >> 16) & 1u)) >> 16);   // RNE
}
__device__ __forceinline__ void gld_lds16_(const unsigned short* g, unsigned short* l) {
    __builtin_amdgcn_global_load_lds((const __attribute__((address_space(1))) unsigned int*)g,
                                     (__attribute__((address_space(3))) unsigned int*)l,
                                     16, 0, 0);
}

// fp32 -> bf16 (RNE), 8 elements/thread
__global__ __launch_bounds__(256)
void f2bf_kernel(const float* __restrict__ src, unsigned short* __restrict__ dst, int n8)
{
    int i = blockIdx.x * 256 + threadIdx.x;
    if (i >= n8) return;
    const float4* s = (const float4*)src + 2 * (size_t)i;
    float4 a = s[0], b = s[1];
    union { unsigned short u[8]; uint4 v; } o;
    o.u[0] = f2bf_(a.x); o.u[1] = f2bf_(a.y); o.u[2] = f2bf_(a.z); o.u[3] = f2bf_(a.w);
    o.u[4] = f2bf_(b.x); o.u[5] = f2bf_(b.y); o.u[6] = f2bf_(b.z); o.u[7] = f2bf_(b.w);
    ((uint4*)dst)[i] = o.v;
}

// ---- bf16 MFMA GEMM (m97 structure) ---------------------------------------
// C[M,N] fp32 = A[M,K] * W[N,K]^T.  128x128 tile, BK=32, 4 waves, 16x16x32.
// MODE 0: plain store. MODE 1: C = softplus(C + bias[col]).
// MODE 2: split destination — cols >= DIN go to C2 (col - DIN), for fused x/z.
template<int MODE>
__global__ __launch_bounds__(256)
void gemm_mfma_bt(const unsigned short* __restrict__ A, const unsigned short* __restrict__ W,
                  float* __restrict__ C, int K, int ldc,
                  const float* __restrict__ bias, float* __restrict__ C2)
{
    __shared__ unsigned short As[128 * 32];
    __shared__ unsigned short Ws[128 * 32];
    const int tid = threadIdx.x;
    const int bm = blockIdx.y << 7;
    int bn = blockIdx.x << 7;

    const int c0 = tid, c1 = tid + 256;
    const unsigned short* ga0 = A + (size_t)(bm + (c0 >> 2)) * K + (c0 & 3) * 8;
    const unsigned short* ga1 = A + (size_t)(bm + (c1 >> 2)) * K + (c1 & 3) * 8;
    const unsigned short* gw0 = W + (size_t)(bn + (c0 >> 2)) * K + (c0 & 3) * 8;
    const unsigned short* gw1 = W + (size_t)(bn + (c1 >> 2)) * K + (c1 & 3) * 8;
    unsigned short* la0 = &As[c0 * 8];
    unsigned short* la1 = &As[c1 * 8];
    unsigned short* lw0 = &Ws[c0 * 8];
    unsigned short* lw1 = &Ws[c1 * 8];

    const int ln  = tid & 63;
    const int wv  = tid >> 6;
    const int wm  = (wv >> 1) << 6;
    const int wn  = (wv & 1) << 6;
    const int m15 = ln & 15;
    const int q   = ln >> 4;

    f32x4 acc[4][4] = {};

    for (int k0 = 0; k0 < K; k0 += 32) {
        __syncthreads();
        gld_lds16_(ga0, la0); gld_lds16_(ga1, la1);
        gld_lds16_(gw0, lw0); gld_lds16_(gw1, lw1);
        ga0 += 32; ga1 += 32; gw0 += 32; gw1 += 32;
        __syncthreads();
        short8 af[4], wf[4];
        #pragma unroll
        for (int i = 0; i < 4; ++i)
            af[i] = *(const short8*)&As[(wm + i * 16 + m15) * 32 + q * 8];
        #pragma unroll
        for (int j = 0; j < 4; ++j)
            wf[j] = *(const short8*)&Ws[(wn + j * 16 + m15) * 32 + q * 8];
        #pragma unroll
        for (int i = 0; i < 4; ++i)
            #pragma unroll
            for (int j = 0; j < 4; ++j)
                acc[i][j] = __builtin_amdgcn_mfma_f32_16x16x32_bf16(af[i], wf[j],
                                                                    acc[i][j], 0, 0, 0);
    }

    float* Cp = C;
    if (MODE == 2 && bn >= DIN) { Cp = C2; bn -= DIN; }   // block-uniform (bn mult of 128)

    #pragma unroll
    for (int i = 0; i < 4; ++i)
        #pragma unroll
        for (int j = 0; j < 4; ++j) {
            int col = bn + wn + j * 16 + m15;
            #pragma unroll
            for (int r = 0; r < 4; ++r) {
                int row = bm + wm + i * 16 + q * 4 + r;
                float v = acc[i][j][r];
                if (MODE == 1) v = softplusf_(v + bias[col]);
                Cp[(size_t)row * ldc + col] = v;
            }
        }
}

// ---- K-split skinny GEMM: partial[kspl][M][160] = A[M, kc] * W[160, kc]^T --
__global__ __launch_bounds__(256)
void gemm_kspl_kernel(const float* __restrict__ A, const float* __restrict__ W,
                      float* __restrict__ partial)
{
    __shared__ float As[16][66];
    __shared__ float Ws[16][162];
    const int tid = threadIdx.x;
    const int tx = tid & 15;
    const int ty = tid >> 4;
    const int bm = blockIdx.x << 6;
    const int k0 = blockIdx.y * KC;

    float acc[4][10] = {};

    for (int kt = 0; kt < KC; kt += 16) {
        float2 a2[2];
        #pragma unroll
        for (int i = 0; i < 2; ++i) {
            int idx = tid + 256 * i;
            int row = idx >> 3, kofs = (idx & 7) * 2;
            a2[i] = *(const float2*)&A[(size_t)(bm + row) * DIN + k0 + kt + kofs];
        }
        float2 w2[5];
        #pragma unroll
        for (int i = 0; i < 5; ++i) {
            int idx = tid + 256 * i;
            int wrow = idx >> 3, wk = (idx & 7) * 2;
            w2[i] = *(const float2*)&W[(size_t)wrow * DIN + k0 + kt + wk];
        }
        __syncthreads();
        #pragma unroll
        for (int i = 0; i < 2; ++i) {
            int idx = tid + 256 * i;
            int row = idx >> 3, kofs = (idx & 7) * 2;
            As[kofs][row] = a2[i].x; As[kofs + 1][row] = a2[i].y;
        }
        #pragma unroll
        for (int i = 0; i < 5; ++i) {
            int idx = tid + 256 * i;
            int wrow = idx >> 3, wk = (idx & 7) * 2;
            Ws[wk][wrow] = w2[i].x; Ws[wk + 1][wrow] = w2[i].y;
        }
        __syncthreads();
        #pragma unroll
        for (int kk = 0; kk < 16; ++kk) {
            float2 av0 = *(const float2*)&As[kk][ty * 4];
            float2 av1 = *(const float2*)&As[kk][ty * 4 + 2];
            float a[4] = {av0.x, av0.y, av1.x, av1.y};
            float w[10];
            #pragma unroll
            for (int j = 0; j < 5; ++j) {
                float2 wv = *(const float2*)&Ws[kk][tx * 10 + 2 * j];
                w[2 * j] = wv.x; w[2 * j + 1] = wv.y;
            }
            #pragma unroll
            for (int i = 0; i < 4; ++i)
                #pragma unroll
                for (int j = 0; j < 10; ++j)
                    acc[i][j] = fmaf(a[i], w[j], acc[i][j]);
        }
        __syncthreads();
    }

    float* po = partial + (size_t)blockIdx.y * NTOK * 160;
    #pragma unroll
    for (int i = 0; i < 4; ++i) {
        int r = bm + ty * 4 + i;
        #pragma unroll
        for (int j = 0; j < 5; ++j)
            *(float2*)&po[(size_t)r * 160 + tx * 10 + 2 * j] =
                make_float2(acc[i][2 * j], acc[i][2 * j + 1]);
    }
}

// sum KSPL partials -> xdbl; also emit bf16 copy of dt_r (cols < 128)
__global__ __launch_bounds__(256)
void kspl_reduce_kernel(const float* __restrict__ partial, float* __restrict__ xdbl,
                        unsigned short* __restrict__ dtr)
{
    int idx = blockIdx.x * 256 + threadIdx.x;   // over NTOK*160
    float s = 0.f;
    #pragma unroll
    for (int k = 0; k < KSPL; ++k)
        s += partial[(size_t)k * NTOK * 160 + idx];
    xdbl[idx] = s;
    int row = idx / 160;
    int col = idx - row * 160;
    if (col < RR) dtr[(size_t)row * RR + col] = f2bf_(s);
}

// Causal depthwise conv (K=4) + SiLU.
__global__ __launch_bounds__(256)
void conv_silu_kernel(const float* __restrict__ x, const float* __restrict__ cw,
                      float* __restrict__ xc)
{
    int idx = blockIdx.x * 256 + threadIdx.x;
    int d = idx & (DIN - 1);
    int tok = idx >> 12;
    int t = tok & (LSEQ - 1);
    float w0 = cw[d * 4 + 0], w1 = cw[d * 4 + 1];
    float w2 = cw[d * 4 + 2], w3 = cw[d * 4 + 3];
    const float* xp = x + (size_t)tok * DIN + d;
    float acc = w3 * xp[0];
    if (t >= 1) acc = fmaf(w2, xp[-DIN], acc);
    if (t >= 2) acc = fmaf(w1, xp[-2 * DIN], acc);
    if (t >= 3) acc = fmaf(w0, xp[-3 * DIN], acc);
    xc[idx] = acc * sigmoidf_(acc);
}

// ---- Chunked parallel selective scan --------------------------------------
__global__ __launch_bounds__(256)
void scan_part1_kernel(const float* __restrict__ delta, const float* __restrict__ xc,
                       const float* __restrict__ xdbl, const float* __restrict__ A_log,
                       float* __restrict__ hloc, float* __restrict__ ssum)
{
    int d = blockIdx.x * 256 + threadIdx.x;
    int c = blockIdx.y;
    int b = blockIdx.z;
    float A[NST], h[NST];
    #pragma unroll
    for (int n = 0; n < NST; ++n) {
        A[n] = -__expf(A_log[d * NST + n]);
        h[n] = 0.f;
    }
    float s = 0.f;
    int tok = b * LSEQ + c * CHUNK;
    for (int t = 0; t < CHUNK; ++t, ++tok) {
        float dv = delta[(size_t)tok * DIN + d];
        float xv = xc[(size_t)tok * DIN + d];
        const float* bc = xdbl + (size_t)tok * 160 + RR;
        float dx = dv * xv;
        s += dv;
        #pragma unroll
        for (int n = 0; n < NST; ++n)
            h[n] = fmaf(h[n], __expf(dv * A[n]), dx * bc[n]);
    }
    size_t base = (size_t)(b * NCH + c) * NST * DIN + d;
    #pragma unroll
    for (int n = 0; n < NST; ++n) hloc[base + (size_t)n * DIN] = h[n];
    ssum[(size_t)(b * NCH + c) * DIN + d] = s;
}

__global__ __launch_bounds__(256)
void scan_part2_kernel(float* __restrict__ hloc, const float* __restrict__ ssum,
                       const float* __restrict__ A_log)
{
    int idx = blockIdx.x * 256 + threadIdx.x;
    int b = idx >> 12;
    int d = idx & (DIN - 1);
    float A[NST], hin[NST];
    #pragma unroll
    for (int n = 0; n < NST; ++n) {
        A[n] = -__expf(A_log[d * NST + n]);
        hin[n] = 0.f;
    }
    for (int c = 0; c < NCH; ++c) {
        size_t base = (size_t)(b * NCH + c) * NST * DIN + d;
        float s = ssum[(size_t)(b * NCH + c) * DIN + d];
        #pragma unroll
        for (int n = 0; n < NST; ++n) {
            float hl = hloc[base + (size_t)n * DIN];
            hloc[base + (size_t)n * DIN] = hin[n];
            hin[n] = fmaf(hin[n], __expf(A[n] * s), hl);
        }
    }
}

__global__ __launch_bounds__(256)
void scan_part3_kernel(const float* __restrict__ delta, float* __restrict__ xcy,
                       const float* __restrict__ xdbl, const float* __restrict__ z,
                       const float* __restrict__ A_log, const float* __restrict__ Dp,
                       const float* __restrict__ hin_buf)
{
    int d = blockIdx.x * 256 + threadIdx.x;
    int c = blockIdx.y;
    int b = blockIdx.z;
    float A[NST], h[NST];
    size_t base = (size_t)(b * NCH + c) * NST * DIN + d;
    #pragma unroll
    for (int n = 0; n < NST; ++n) {
        A[n] = -__expf(A_log[d * NST + n]);
        h[n] = hin_buf[base + (size_t)n * DIN];
    }
    float Dv = Dp[d];
    int tok = b * LSEQ + c * CHUNK;
    for (int t = 0; t < CHUNK; ++t, ++tok) {
        float dv = delta[(size_t)tok * DIN + d];
        float xv = xcy[(size_t)tok * DIN + d];
        float zv = z[(size_t)tok * DIN + d];
        const float* bc = xdbl + (size_t)tok * 160 + RR;
        float dx = dv * xv;
        float y = 0.f;
        #pragma unroll
        for (int n = 0; n < NST; ++n) {
            h[n] = fmaf(h[n], __expf(dv * A[n]), dx * bc[n]);
            y = fmaf(h[n], bc[NST + n], y);
        }
        y = (y + xv * Dv) * (zv * sigmoidf_(zv));
        xcy[(size_t)tok * DIN + d] = y;
    }
}

extern "C" void kernel_launch(void* const* d_in, const int* in_sizes, int n_in,
                              void* d_out, int out_size, void* d_ws, size_t ws_size,
                              hipStream_t stream)
{
    const float* hidden     = (const float*)d_in[0];
    const float* in_proj_w  = (const float*)d_in[1];
    const float* conv_w     = (const float*)d_in[2];
    const float* x_proj_w   = (const float*)d_in[3];
    const float* dt_proj_w  = (const float*)d_in[4];
    const float* dt_bias    = (const float*)d_in[5];
    const float* A_log      = (const float*)d_in[6];
    const float* D_param    = (const float*)d_in[7];
    const float* out_proj_w = (const float*)d_in[8];
    float* out = (float*)d_out;

    // Workspace: 3 x 67.1 MB + 2.6 MB = 204 MB (known-safe footprint)
    const size_t BIG = (size_t)NTOK * DIN * sizeof(float);
    char* ws = (char*)d_ws;
    float* xbuf = (float*)(ws);                              // x -> delta -> y_bf
    float* xc   = (float*)(ws + BIG);                        // w_in_bf -> xc/y
    float* zbuf = (float*)(ws + 2 * BIG);                    // z -> w_out_bf
    float* xdbl = (float*)(ws + 3 * BIG);                    // 2.6 MB
    float* delta = xbuf;

    // bf16 staging buffers in dead regions:
    unsigned short* w_in_bf  = (unsigned short*)xc;          // dies at conv
    unsigned short* hid_bf   = (unsigned short*)out;         // dies after G1
    unsigned short* y_bf     = (unsigned short*)xbuf;        // after delta dead
    unsigned short* w_out_bf = (unsigned short*)zbuf;        // after z dead

    // d_out scratch (33.5 MB), time-multiplexed:
    //   hid_bf (16.8 MB, steps 0-1) -> kspl partial (21 MB) + dtr/dtw bf16 (21-23 MB)
    //   -> hloc+ssum (17.8 MB, step 5) -> final GEMM output (step 6)
    float* xpart = out;                                          // 21 MB
    unsigned short* dtr_bf = (unsigned short*)(out + (size_t)KSPL * NTOK * 160);  // 1 MB
    unsigned short* dtw_bf = dtr_bf + (size_t)NTOK * RR;                          // 1 MB
    float* hloc  = out;
    float* ssum  = out + (size_t)BB * NCH * NST * DIN;

    // 0) fp32 -> bf16 for GEMM1
    f2bf_kernel<<<8192, 256, 0, stream>>>(in_proj_w, w_in_bf, (2 * DIN * 2048) / 8);
    f2bf_kernel<<<4096, 256, 0, stream>>>(hidden, hid_bf, (NTOK * 2048) / 8);
    // 1) x | z = hidden @ in_proj_w^T (bf16 MFMA, fused split-dest, N=8192)
    gemm_mfma_bt<2><<<dim3(64, 32), 256, 0, stream>>>(hid_bf, w_in_bf, xbuf,
                                                      2048, DIN, nullptr, zbuf);
    // 2) xc = silu(causal_conv(x))
    conv_silu_kernel<<<(NTOK * DIN) / 256, 256, 0, stream>>>(xbuf, conv_w, xc);
    // 3) x_dbl = xc @ x_proj_w^T  (K-split fp32 + reduce; reduce also emits dt_r bf16)
    gemm_kspl_kernel<<<dim3(NTOK / 64, KSPL), 256, 0, stream>>>(xc, x_proj_w, xpart);
    kspl_reduce_kernel<<<(NTOK * 160) / 256, 256, 0, stream>>>(xpart, xdbl, dtr_bf);
    // 4) delta = softplus(dt_r @ dt_proj_w^T + bias)  (bf16 MFMA, K=128)
    f2bf_kernel<<<256, 256, 0, stream>>>(dt_proj_w, dtw_bf, (DIN * RR) / 8);
    gemm_mfma_bt<1><<<dim3(32, 32), 256, 0, stream>>>(dtr_bf, dtw_bf, delta,
                                                      RR, DIN, dt_bias, nullptr);
    // 5) chunked selective scan
    scan_part1_kernel<<<dim3(DIN / 256, NCH, BB), 256, 0, stream>>>(delta, xc, xdbl,
                                                                    A_log, hloc, ssum);
    scan_part2_kernel<<<(BB * DIN) / 256, 256, 0, stream>>>(hloc, ssum, A_log);
    scan_part3_kernel<<<dim3(DIN / 256, NCH, BB), 256, 0, stream>>>(delta, xc, xdbl,
                                                                    zbuf, A_log, D_param, hloc);
    // 5c) convert for final GEMM
    f2bf_kernel<<<8192, 256, 0, stream>>>(xc, y_bf, (NTOK * DIN) / 8);
    f2bf_kernel<<<4096, 256, 0, stream>>>(out_proj_w, w_out_bf, (2048 * DIN) / 8);
    // 6) out = y @ out_proj_w^T (bf16 MFMA)
    gemm_mfma_bt<0><<<dim3(16, 32), 256, 0, stream>>>(y_bf, w_out_bf, out,
                                                      4096, 2048, nullptr, nullptr);
}